// Round 2
// baseline (524.657 us; speedup 1.0000x reference)
//
#include <hip/hip_runtime.h>
#include <stdint.h>

#define IN_FEATS 128
#define OUT_FEATS 256
#define TOPK 32
#define BM 128
#define BN 128
#define BK 64      /* K-step: 64 bf16 = 128 B row = 8x 16B chunks */
#define KTOT 256

typedef float f32x4 __attribute__((ext_vector_type(4)));
typedef short bf16x8 __attribute__((ext_vector_type(8)));

__device__ __forceinline__ unsigned short f2bf(float x) {
    unsigned u = __float_as_uint(x);
    u += 0x7FFFu + ((u >> 16) & 1u);   // round-to-nearest-even
    return (unsigned short)(u >> 16);
}

// async 16B global -> LDS (linear dest: wave-uniform base + lane*16)
__device__ __forceinline__ void gload16(const void* g, void* l) {
    __builtin_amdgcn_global_load_lds(
        (const __attribute__((address_space(1))) unsigned*)g,
        (__attribute__((address_space(3))) unsigned*)l, 16, 0, 0);
}

// K1: pack top-k (value,index) -> uint32 [(bf16val)<<16 | idx], [N,32].
// Replaces the dense x_sparse materialization: the aggregation gathers these
// 128B rows instead of 256B dense rows (halves gather demand).
// Value unpack is free: __uint_as_float(u & 0xFFFF0000) IS bf16->f32.
__global__ void k_pack(const float* __restrict__ vals, const int* __restrict__ idxs,
                       unsigned* __restrict__ packed, int total) {
    int i = blockIdx.x * 256 + threadIdx.x;
    if (i >= total) return;
    packed[i] = ((unsigned)f2bf(vals[i]) << 16) | ((unsigned)idxs[i] & 127u);
}

// Kw: build W^T bf16 [256 outs][256 ks], rows = output col, concat K = [W_neigh; W_self]
__global__ void k_weights(const float* __restrict__ Wn, const float* __restrict__ Ws,
                          unsigned short* __restrict__ WT) {
    int idx = blockIdx.x * 256 + threadIdx.x;   // 0..65535
    int n = idx >> 8;
    int k = idx & 255;
    float v = (k < IN_FEATS) ? Wn[(size_t)k * OUT_FEATS + n]
                             : Ws[(size_t)(k - IN_FEATS) * OUT_FEATS + n];
    WT[idx] = f2bf(v);
}

// Ki: build indptr[N+1] from sorted row[] (edge-parallel, writes gap ranges).
__global__ void k_indptr(const int* __restrict__ row, int* __restrict__ indptr,
                         int n_nodes, int n_edges) {
    int e = blockIdx.x * 256 + threadIdx.x;
    if (e >= n_edges) return;
    int r = row[e];
    int rp = (e == 0) ? -1 : row[e - 1];
    for (int x = rp + 1; x <= r; ++x) indptr[x] = e;
    if (e == n_edges - 1)
        for (int x = r + 1; x <= n_nodes; ++x) indptr[x] = n_edges;
}

// K2: mean aggregation via sparse gather + LDS scatter-add.
// One wave per node, 4 nodes/block. Per edge: a 16-lane group reads the
// node's 32 packed pairs (uint2/lane = 2 pairs) and ds_add_f32's them into
// the wave's private 128-float LDS accumulator. Duplicate indices accumulate
// (matches reference .add). Invalid edges predicated by scale=0 (adds 0).
// Also converts feat f32->bf16 into Acat[node][128:256] (coalesced).
__global__ __launch_bounds__(256) void k_aggregate(
    const unsigned* __restrict__ packed,
    const float* __restrict__ feat,
    const int* __restrict__ indptr, const int* __restrict__ col,
    unsigned short* __restrict__ Acat, int n_nodes) {
    __shared__ float acc[4 * IN_FEATS];   // 2 KB: 128 floats per wave/node
    int t = threadIdx.x;
    int wv = t >> 6;
    int lane = t & 63;
    int node = blockIdx.x * 4 + wv;
    bool valid = node < n_nodes;
    int nodec = valid ? node : (n_nodes - 1);

    acc[t] = 0.f;
    acc[t + 256] = 0.f;
    __syncthreads();

    int e0 = indptr[nodec];
    int e1 = indptr[nodec + 1];
    if (!valid) e1 = e0;                  // tail waves: no work, keep barriers uniform
    int eg = lane >> 4, fi = lane & 15;
    float* macc = acc + wv * IN_FEATS;

    int elast = (e1 > e0) ? (e1 - 1) : e0;
    for (int base = e0; base < e1; base += 8) {
        int ea = base + eg;
        int eb = base + 4 + eg;
        float sa = (ea < e1) ? 1.f : 0.f;
        float sb = (eb < e1) ? 1.f : 0.f;
        int ca = col[ea < elast ? ea : elast];
        int cb = col[eb < elast ? eb : elast];
        uint2 ua = *(const uint2*)(packed + (size_t)ca * TOPK + fi * 2);
        uint2 ub = *(const uint2*)(packed + (size_t)cb * TOPK + fi * 2);
        atomicAdd(&macc[ua.x & 127u], __uint_as_float(ua.x & 0xFFFF0000u) * sa);
        atomicAdd(&macc[ua.y & 127u], __uint_as_float(ua.y & 0xFFFF0000u) * sa);
        atomicAdd(&macc[ub.x & 127u], __uint_as_float(ub.x & 0xFFFF0000u) * sb);
        atomicAdd(&macc[ub.y & 127u], __uint_as_float(ub.y & 0xFFFF0000u) * sb);
    }
    __syncthreads();   // conservative: guarantee LDS atomic visibility before read

    if (valid) {
        if (eg == 0) {
            int cnt = e1 - e0;
            float inv = 1.0f / (float)(cnt > 0 ? cnt : 1);  // == 1/max(deg,1)
            unsigned o[4];
#pragma unroll
            for (int i = 0; i < 4; ++i) {
                unsigned lo = f2bf(macc[fi * 8 + 2 * i] * inv);
                unsigned hi = f2bf(macc[fi * 8 + 2 * i + 1] * inv);
                o[i] = lo | (hi << 16);
            }
            *(uint4*)(Acat + (size_t)node * KTOT + fi * 8) = *(uint4*)&o[0];
        }
        // featb: all 64 lanes, 2 floats each -> bf16x2 packed, 4B/lane store
        float2 fv = *(const float2*)(feat + (size_t)node * IN_FEATS + lane * 2);
        unsigned pk = (unsigned)f2bf(fv.x) | ((unsigned)f2bf(fv.y) << 16);
        *(unsigned*)(Acat + (size_t)node * KTOT + IN_FEATS + lane * 2) = pk;
    }
}

// K3: rst = Acat @ WT^T + bias.  M=n_nodes, K=256, N=256, all-bf16 A/B.
// m97 structure: global_load_lds width-16 staging, BK=64, single-buffered LDS.
// LDS kept LINEAR for global_load_lds; bank spread via chunk swizzle q ^= (row&7)
// applied identically to the global SOURCE address and the ds_read address
// (rule #21: both-sides-or-neither).
__global__ __launch_bounds__(256) void k_gemm(
    const unsigned short* __restrict__ Acat,  // [N,256] bf16
    const unsigned short* __restrict__ WT,    // [256][256] bf16, WT[n][k]
    const float* __restrict__ bias,
    float* __restrict__ out, int n_nodes) {
    __shared__ __align__(16) unsigned short Ash[BM * BK];  // 16 KB, swizzled content
    __shared__ __align__(16) unsigned short Bsh[BN * BK];  // 16 KB
    int t = threadIdx.x;
    int m0 = blockIdx.x * BM;
    int n0 = blockIdx.y * BN;
    int lane = t & 63;
    int w = t >> 6;
    int wr = w >> 1, wc = w & 1;
    int lrow = lane & 15, quad = lane >> 4;

    f32x4 acc[4][4];
#pragma unroll
    for (int i = 0; i < 4; ++i)
#pragma unroll
        for (int j = 0; j < 4; ++j)
            acc[i][j] = (f32x4){0.f, 0.f, 0.f, 0.f};

    for (int kk = 0; kk < KTOT; kk += BK) {
        // ---- stage A and B tiles: 1024 16B chunks each, 4 chunks/thread ----
#pragma unroll
        for (int p = 0; p < 4; ++p) {
            int c = p * 256 + t;             // wave-contiguous: lanes consecutive
            int row = c >> 3;
            int q = (c & 7) ^ (row & 7);     // inverse-swizzled global source
            int nodeA = m0 + row;
            if (nodeA >= n_nodes) nodeA = n_nodes - 1;   // clamp, in-bounds read
            gload16(Acat + (size_t)nodeA * KTOT + kk + q * 8, &Ash[(size_t)c * 8]);
            gload16(WT + (size_t)(n0 + row) * KTOT + kk + q * 8, &Bsh[(size_t)c * 8]);
        }
        __syncthreads();

#pragma unroll
        for (int ks = 0; ks < 2; ++ks) {     // two 16x16x32 K-substeps per BK=64
            bf16x8 af[4], bfr[4];
#pragma unroll
            for (int mi = 0; mi < 4; ++mi) {
                int r = wr * 64 + mi * 16 + lrow;
                int q = (ks * 4 + quad) ^ (r & 7);       // swizzled read
                af[mi] = *(const bf16x8*)&Ash[(r * 8 + q) * 8];
            }
#pragma unroll
            for (int ni = 0; ni < 4; ++ni) {
                int r = wc * 64 + ni * 16 + lrow;
                int q = (ks * 4 + quad) ^ (r & 7);
                bfr[ni] = *(const bf16x8*)&Bsh[(r * 8 + q) * 8];
            }
#pragma unroll
            for (int mi = 0; mi < 4; ++mi)
#pragma unroll
                for (int ni = 0; ni < 4; ++ni)
                    acc[mi][ni] = __builtin_amdgcn_mfma_f32_16x16x32_bf16(
                        af[mi], bfr[ni], acc[mi][ni], 0, 0, 0);
        }
        __syncthreads();
    }

    // epilogue: C/D layout col=lane&15, row=quad*4+reg
#pragma unroll
    for (int mi = 0; mi < 4; ++mi) {
        int gm = m0 + wr * 64 + mi * 16 + quad * 4;
#pragma unroll
        for (int ni = 0; ni < 4; ++ni) {
            int go = n0 + wc * 64 + ni * 16 + lrow;
            float b = bias[go];
#pragma unroll
            for (int r = 0; r < 4; ++r) {
                int node = gm + r;
                if (node < n_nodes)
                    out[(size_t)node * OUT_FEATS + go] = acc[mi][ni][r] + b;
            }
        }
    }
}

extern "C" void kernel_launch(void* const* d_in, const int* in_sizes, int n_in,
                              void* d_out, int out_size, void* d_ws, size_t ws_size,
                              hipStream_t stream) {
    const float* feat = (const float*)d_in[0];
    const float* tkv  = (const float*)d_in[1];
    const int*   tki  = (const int*)d_in[2];
    const int*   row  = (const int*)d_in[3];
    const int*   col  = (const int*)d_in[4];
    const float* Wn   = (const float*)d_in[6];
    const float* Ws   = (const float*)d_in[7];
    const float* bias = (const float*)d_in[8];
    float* out = (float*)d_out;

    int n_nodes = in_sizes[5];
    int n_edges = in_sizes[3];

    // ws layout: packed u32 [N,32] | Acat bf16 [N,256] | WT bf16 [256,256] | indptr [N+1]
    unsigned* packed = (unsigned*)d_ws;
    unsigned short* Acat = (unsigned short*)(packed + (size_t)n_nodes * TOPK);
    unsigned short* WT   = Acat + (size_t)n_nodes * KTOT;
    int* indptr = (int*)(WT + (size_t)OUT_FEATS * KTOT);

    int total = n_nodes * TOPK;
    k_pack<<<(total + 255) / 256, 256, 0, stream>>>(tkv, tki, packed, total);
    k_weights<<<256, 256, 0, stream>>>(Wn, Ws, WT);
    k_indptr<<<(n_edges + 255) / 256, 256, 0, stream>>>(row, indptr, n_nodes, n_edges);
    k_aggregate<<<(n_nodes + 3) / 4, 256, 0, stream>>>(packed, feat, indptr, col, Acat, n_nodes);
    dim3 g3((n_nodes + BM - 1) / BM, OUT_FEATS / BN);
    k_gemm<<<g3, 256, 0, stream>>>(Acat, WT, bias, out, n_nodes);
}

// Round 3
// 289.411 us; speedup vs baseline: 1.8128x; 1.8128x over previous
//
#include <hip/hip_runtime.h>
#include <stdint.h>

#define IN_FEATS 128
#define OUT_FEATS 256
#define TOPK 32
#define BM 128
#define BN 128
#define BK 64      /* K-step: 64 bf16 = 128 B row = 8x 16B chunks */
#define KTOT 256

typedef float f32x4 __attribute__((ext_vector_type(4)));
typedef short bf16x8 __attribute__((ext_vector_type(8)));

__device__ __forceinline__ unsigned short f2bf(float x) {
    unsigned u = __float_as_uint(x);
    u += 0x7FFFu + ((u >> 16) & 1u);   // round-to-nearest-even
    return (unsigned short)(u >> 16);
}

// async 16B global -> LDS (linear dest: wave-uniform base + lane*16)
__device__ __forceinline__ void gload16(const void* g, void* l) {
    __builtin_amdgcn_global_load_lds(
        (const __attribute__((address_space(1))) unsigned*)g,
        (__attribute__((address_space(3))) unsigned*)l, 16, 0, 0);
}

// K1: scatter top-k into dense bf16 x_sparse [N,128], 4 nodes/block.
// Duplicate indices ACCUMULATE (reference .add) -> atomicAdd in LDS.
// Fused: feat f32->bf16 convert into Acat[:,128:256] (coalesced streaming),
// piggybacked here because this kernel is latency-bound with idle BW.
__global__ __launch_bounds__(256) void k_scatter(
    const float* __restrict__ vals, const int* __restrict__ idxs,
    const float* __restrict__ feat,
    unsigned short* __restrict__ xsp, unsigned short* __restrict__ Acat,
    int n_nodes) {
    __shared__ float lds[4 * IN_FEATS];
    int t = threadIdx.x;
    int n0 = blockIdx.x * 4;
    lds[t] = 0.f;
    lds[t + 256] = 0.f;
    __syncthreads();
    if (t < 4 * TOPK) {
        int h = t >> 5;          // which of the 4 nodes
        int k = t & 31;
        int n = n0 + h;
        if (n < n_nodes) {
            float v = vals[(size_t)n * TOPK + k];
            int ix = idxs[(size_t)n * TOPK + k] & 127;
            atomicAdd(&lds[h * IN_FEATS + ix], v);
        }
    }
    __syncthreads();
    // 64 threads per node, 2 consecutive feats each -> packed u32 stores
    int h2 = t >> 6;
    int f2 = (t & 63) * 2;
    int n = n0 + h2;
    if (n < n_nodes) {
        unsigned lo = f2bf(lds[h2 * IN_FEATS + f2]);
        unsigned hi = f2bf(lds[h2 * IN_FEATS + f2 + 1]);
        *(unsigned*)(xsp + (size_t)n * IN_FEATS + f2) = lo | (hi << 16);
        float2 fv = *(const float2*)(feat + (size_t)n * IN_FEATS + f2);
        unsigned pk = (unsigned)f2bf(fv.x) | ((unsigned)f2bf(fv.y) << 16);
        *(unsigned*)(Acat + (size_t)n * KTOT + IN_FEATS + f2) = pk;
    }
}

// Kw: build W^T bf16 [256 outs][256 ks], rows = output col, concat K = [W_neigh; W_self]
__global__ void k_weights(const float* __restrict__ Wn, const float* __restrict__ Ws,
                          unsigned short* __restrict__ WT) {
    int idx = blockIdx.x * 256 + threadIdx.x;   // 0..65535
    int n = idx >> 8;
    int k = idx & 255;
    float v = (k < IN_FEATS) ? Wn[(size_t)k * OUT_FEATS + n]
                             : Ws[(size_t)(k - IN_FEATS) * OUT_FEATS + n];
    WT[idx] = f2bf(v);
}

// Ki: build indptr[N+1] from sorted row[] (edge-parallel, writes gap ranges).
__global__ void k_indptr(const int* __restrict__ row, int* __restrict__ indptr,
                         int n_nodes, int n_edges) {
    int e = blockIdx.x * 256 + threadIdx.x;
    if (e >= n_edges) return;
    int r = row[e];
    int rp = (e == 0) ? -1 : row[e - 1];
    for (int x = rp + 1; x <= r; ++x) indptr[x] = e;
    if (e == n_edges - 1)
        for (int x = r + 1; x <= n_nodes; ++x) indptr[x] = n_edges;
}

// K2: mean aggregation -> Acat[node][0:128]. One wave per node, 4 nodes/block.
// lane = eg*16 + fi: 16 lanes x 16B cover one bf16 feature row; 4 edge groups
// x 4-deep unroll -> 16 dense-row gathers in flight per wave (avg degree = 16,
// so most waves issue their whole edge list in one burst). Register
// accumulate only -- no LDS, no atomics (round-2 lesson: LDS scatter-add
// serializes 4x worse than the extra gather bytes cost).
__global__ __launch_bounds__(256) void k_aggregate(
    const unsigned short* __restrict__ xsp,
    const int* __restrict__ indptr, const int* __restrict__ col,
    unsigned short* __restrict__ Acat, int n_nodes) {
    int t = threadIdx.x;
    int node = blockIdx.x * 4 + (t >> 6);
    if (node >= n_nodes) return;
    int lane = t & 63;
    int eg = lane >> 4, fi = lane & 15;
    int e0 = indptr[node], e1 = indptr[node + 1];

    float acc[8] = {0.f, 0.f, 0.f, 0.f, 0.f, 0.f, 0.f, 0.f};
    int elast = (e1 > e0) ? (e1 - 1) : e0;
    for (int base = e0; base < e1; base += 16) {
        float s[4];
        int c[4];
        uint4 u[4];
#pragma unroll
        for (int j = 0; j < 4; ++j) {
            int ee = base + j * 4 + eg;
            s[j] = (ee < e1) ? 1.f : 0.f;
            c[j] = col[ee < elast ? ee : elast];
        }
#pragma unroll
        for (int j = 0; j < 4; ++j)
            u[j] = *(const uint4*)(xsp + (size_t)c[j] * IN_FEATS + fi * 8);
#pragma unroll
        for (int j = 0; j < 4; ++j) {
            unsigned p[4] = {u[j].x, u[j].y, u[j].z, u[j].w};
#pragma unroll
            for (int i = 0; i < 4; ++i) {
                acc[2 * i]     = fmaf(s[j], __uint_as_float(p[i] << 16), acc[2 * i]);
                acc[2 * i + 1] = fmaf(s[j], __uint_as_float(p[i] & 0xFFFF0000u), acc[2 * i + 1]);
            }
        }
    }
    // reduce across the 4 edge subgroups (stride 16, 32)
#pragma unroll
    for (int i = 0; i < 8; ++i) {
        acc[i] += __shfl_down(acc[i], 16, 64);
        acc[i] += __shfl_down(acc[i], 32, 64);
    }
    if (eg == 0) {
        int cnt = e1 - e0;
        float inv = 1.0f / (float)(cnt > 0 ? cnt : 1);  // == 1/max(deg,1)
        unsigned o[4];
#pragma unroll
        for (int i = 0; i < 4; ++i) {
            unsigned lo = f2bf(acc[2 * i] * inv);
            unsigned hi = f2bf(acc[2 * i + 1] * inv);
            o[i] = lo | (hi << 16);
        }
        *(uint4*)(Acat + (size_t)node * KTOT + fi * 8) = *(uint4*)&o[0];
    }
}

// K3: rst = Acat @ WT^T + bias.  M=n_nodes, K=256, N=256, all-bf16 A/B.
// m97 structure: global_load_lds width-16 staging, BK=64, single-buffered LDS.
// LDS kept LINEAR for global_load_lds; bank spread via chunk swizzle q ^= (row&7)
// applied identically to the global SOURCE address and the ds_read address
// (rule #21: both-sides-or-neither).
__global__ __launch_bounds__(256) void k_gemm(
    const unsigned short* __restrict__ Acat,  // [N,256] bf16
    const unsigned short* __restrict__ WT,    // [256][256] bf16, WT[n][k]
    const float* __restrict__ bias,
    float* __restrict__ out, int n_nodes) {
    __shared__ __align__(16) unsigned short Ash[BM * BK];  // 16 KB, swizzled content
    __shared__ __align__(16) unsigned short Bsh[BN * BK];  // 16 KB
    int t = threadIdx.x;
    int m0 = blockIdx.x * BM;
    int n0 = blockIdx.y * BN;
    int lane = t & 63;
    int w = t >> 6;
    int wr = w >> 1, wc = w & 1;
    int lrow = lane & 15, quad = lane >> 4;

    f32x4 acc[4][4];
#pragma unroll
    for (int i = 0; i < 4; ++i)
#pragma unroll
        for (int j = 0; j < 4; ++j)
            acc[i][j] = (f32x4){0.f, 0.f, 0.f, 0.f};

    for (int kk = 0; kk < KTOT; kk += BK) {
        // ---- stage A and B tiles: 1024 16B chunks each, 4 chunks/thread ----
#pragma unroll
        for (int p = 0; p < 4; ++p) {
            int c = p * 256 + t;             // wave-contiguous: lanes consecutive
            int row = c >> 3;
            int q = (c & 7) ^ (row & 7);     // inverse-swizzled global source
            int nodeA = m0 + row;
            if (nodeA >= n_nodes) nodeA = n_nodes - 1;   // clamp, in-bounds read
            gload16(Acat + (size_t)nodeA * KTOT + kk + q * 8, &Ash[(size_t)c * 8]);
            gload16(WT + (size_t)(n0 + row) * KTOT + kk + q * 8, &Bsh[(size_t)c * 8]);
        }
        __syncthreads();

#pragma unroll
        for (int ks = 0; ks < 2; ++ks) {     // two 16x16x32 K-substeps per BK=64
            bf16x8 af[4], bfr[4];
#pragma unroll
            for (int mi = 0; mi < 4; ++mi) {
                int r = wr * 64 + mi * 16 + lrow;
                int q = (ks * 4 + quad) ^ (r & 7);       // swizzled read
                af[mi] = *(const bf16x8*)&Ash[(r * 8 + q) * 8];
            }
#pragma unroll
            for (int ni = 0; ni < 4; ++ni) {
                int r = wc * 64 + ni * 16 + lrow;
                int q = (ks * 4 + quad) ^ (r & 7);
                bfr[ni] = *(const bf16x8*)&Bsh[(r * 8 + q) * 8];
            }
#pragma unroll
            for (int mi = 0; mi < 4; ++mi)
#pragma unroll
                for (int ni = 0; ni < 4; ++ni)
                    acc[mi][ni] = __builtin_amdgcn_mfma_f32_16x16x32_bf16(
                        af[mi], bfr[ni], acc[mi][ni], 0, 0, 0);
        }
        __syncthreads();
    }

    // epilogue: C/D layout col=lane&15, row=quad*4+reg
#pragma unroll
    for (int mi = 0; mi < 4; ++mi) {
        int gm = m0 + wr * 64 + mi * 16 + quad * 4;
#pragma unroll
        for (int ni = 0; ni < 4; ++ni) {
            int go = n0 + wc * 64 + ni * 16 + lrow;
            float b = bias[go];
#pragma unroll
            for (int r = 0; r < 4; ++r) {
                int node = gm + r;
                if (node < n_nodes)
                    out[(size_t)node * OUT_FEATS + go] = acc[mi][ni][r] + b;
            }
        }
    }
}

extern "C" void kernel_launch(void* const* d_in, const int* in_sizes, int n_in,
                              void* d_out, int out_size, void* d_ws, size_t ws_size,
                              hipStream_t stream) {
    const float* feat = (const float*)d_in[0];
    const float* tkv  = (const float*)d_in[1];
    const int*   tki  = (const int*)d_in[2];
    const int*   row  = (const int*)d_in[3];
    const int*   col  = (const int*)d_in[4];
    const float* Wn   = (const float*)d_in[6];
    const float* Ws   = (const float*)d_in[7];
    const float* bias = (const float*)d_in[8];
    float* out = (float*)d_out;

    int n_nodes = in_sizes[5];
    int n_edges = in_sizes[3];

    // ws layout: xsp bf16 [N,128] | Acat bf16 [N,256] | WT bf16 [256,256] | indptr [N+1]
    unsigned short* xsp  = (unsigned short*)d_ws;
    unsigned short* Acat = xsp + (size_t)n_nodes * IN_FEATS;
    unsigned short* WT   = Acat + (size_t)n_nodes * KTOT;
    int* indptr = (int*)(WT + (size_t)OUT_FEATS * KTOT);

    k_scatter<<<(n_nodes + 3) / 4, 256, 0, stream>>>(tkv, tki, feat, xsp, Acat, n_nodes);
    k_weights<<<256, 256, 0, stream>>>(Wn, Ws, WT);
    k_indptr<<<(n_edges + 255) / 256, 256, 0, stream>>>(row, indptr, n_nodes, n_edges);
    k_aggregate<<<(n_nodes + 3) / 4, 256, 0, stream>>>(xsp, indptr, col, Acat, n_nodes);
    dim3 g3((n_nodes + BM - 1) / BM, OUT_FEATS / BN);
    k_gemm<<<g3, 256, 0, stream>>>(Acat, WT, bias, out, n_nodes);
}